// Round 17
// baseline (274.660 us; speedup 1.0000x reference)
//
#include <hip/hip_runtime.h>
#include <hip/hip_fp16.h>
#include <math.h>

// 2-layer GAT. N=50000, E=800000 (+N self loops), F=128, H=8, C=32, NCLS=16.
// R17: K2 attacked structurally after R16's A/B killed the load-batching theory.
// (a) gemm1: W1t staged in LDS once per BLOCK (264B-padded rows, ~4-way conflict
//     = 1.58x ok). Was: every WAVE streamed 64KB W1t from L2 (200MB aggregate,
//     L1 can't hold it) -> now 50MB L2 + LDS reads. A-frags straight from
//     global x with fp32->f16 convert (A-staging pass deleted).
// (b) scan: partial transposed to tile-major partial3[g/64][chunk][g%64] --
//     wave (lane=bin) STREAMS 128 contiguous 128B rows per tile instead of
//     128 loads at 100KB stride. Scan blocks = 196 (256 bins each).
//   K1 histW | K2 scan+gemm1 | K3 scatter3+rowfin | K4 agg1 | K5 gemm2 | K6 agg2

#define NC    128          // edge chunks
#define NBK   256          // hist/scatter blocks = NC * 2 halves
#define NBINS 50000
#define HBINS 25000        // bins per half
#define NWH   12500        // packed u32 words per half (2 bins each)
#define NTILE 782          // bin tiles of 64 (50048 padded)

typedef _Float16 f16x8 __attribute__((ext_vector_type(8)));
typedef _Float16 f16x4 __attribute__((ext_vector_type(4)));
typedef float    f32x4 __attribute__((ext_vector_type(4)));

__device__ __forceinline__ float lrelu(float v){ return v > 0.f ? v : 0.2f*v; }

// partial3 index for (chunk c, bin g): ((g>>6)*128 + c)*64 + (g&63)   [u16]
__device__ __forceinline__ size_t p3idx(int g, int c){
  return ((size_t)(g>>6)*128 + c)*64 + (g&63);
}

// ---------------- K1: hist (packed u16 LDS) -> partial3 (tile-major) + weight prep ----------------
__global__ __launch_bounds__(256) void k_histW(const int* __restrict__ dstv,
    unsigned short* __restrict__ partial3, int E, int Etot, int chunk,
    const float* __restrict__ W1, _Float16* __restrict__ W1t,
    const float* __restrict__ W2, _Float16* __restrict__ W2t)
{
  int b = blockIdx.x, t = threadIdx.x;
  if (b >= NBK){
    int b2 = b - NBK;
    if (b2 < 128){
      W1t[t*128 + b2] = (_Float16)W1[b2*256 + t];
    } else {
      for (int i=t; i<4096; i+=256){ int k=i&255, j=i>>8; W2t[j*256+k] = (_Float16)W2[k*16+j]; }
    }
    return;
  }
  __shared__ unsigned int cnt[NWH];         // 50 KB -> 2 blocks/CU
  int c = b >> 1, half = b & 1, lo = half*HBINS;
  for (int i=t; i<NWH; i+=256) cnt[i] = 0u;
  __syncthreads();
  int e0 = c*chunk, e1 = e0+chunk; if (e1 > Etot) e1 = Etot;
  int e = e0 + t;
  for (; e + 768 < e1; e += 1024){
    int ea=e, eb=e+256, ec=e+512, ed=e+768;
    int d0 = (ea<E)?dstv[ea]:(ea-E);
    int d1 = (eb<E)?dstv[eb]:(eb-E);
    int d2 = (ec<E)?dstv[ec]:(ec-E);
    int d3 = (ed<E)?dstv[ed]:(ed-E);
    int r0=d0-lo, r1=d1-lo, r2=d2-lo, r3=d3-lo;
    if (r0>=0 && r0<HBINS) atomicAdd(&cnt[r0>>1], (r0&1)?65536u:1u);
    if (r1>=0 && r1<HBINS) atomicAdd(&cnt[r1>>1], (r1&1)?65536u:1u);
    if (r2>=0 && r2<HBINS) atomicAdd(&cnt[r2>>1], (r2&1)?65536u:1u);
    if (r3>=0 && r3<HBINS) atomicAdd(&cnt[r3>>1], (r3&1)?65536u:1u);
  }
  for (; e < e1; e += 256){
    int d = (e<E)?dstv[e]:(e-E);
    int r = d - lo;
    if (r>=0 && r<HBINS) atomicAdd(&cnt[r>>1], (r&1)?65536u:1u);
  }
  __syncthreads();
  // write out tile-major: wave's 64 consecutive bins = one 128B row (coalesced)
  for (int i=t; i<HBINS; i+=256){
    int g = lo + i;
    unsigned int w = cnt[i>>1];
    unsigned short val = (i&1) ? (unsigned short)(w>>16) : (unsigned short)(w&0xffffu);
    partial3[p3idx(g, c)] = val;
  }
}

// ---------------- K2: scan (blocks 0..SB2-1, tile-streaming) + GEMM1 (LDS-B) ----------------
__global__ __launch_bounds__(256) void k_g1scan(const float* __restrict__ x,
    const _Float16* __restrict__ W1t, const float* __restrict__ as1,
    const float* __restrict__ ad1, _Float16* __restrict__ h1,
    float* __restrict__ a_src1, float* __restrict__ a_dst1,
    unsigned short* __restrict__ partial3, int* __restrict__ rowptr,
    int* __restrict__ bsum, int N, int SB2)
{
  __shared__ char smem[67584];              // gemm1: Bs [256][264B]; scan: 1KB
  int t = threadIdx.x;
  int b = blockIdx.x;

  if (b < SB2){
    // ---- scan: thread owns bin g = b*256 + t; wave streams its tile rows ----
    int* lds = (int*)smem;
    int g = b*256 + t;
    bool live = g < NBINS;
    int tile = g >> 6, ofs = g & 63;
    int run = 0;
    for (int c0=0; c0<NC; c0+=8){
      unsigned short v[8];
      #pragma unroll
      for (int j=0;j<8;++j)
        v[j] = live ? partial3[((size_t)tile*128 + c0+j)*64 + ofs] : (unsigned short)0;
      #pragma unroll
      for (int j=0;j<8;++j){
        if (live) partial3[((size_t)tile*128 + c0+j)*64 + ofs] = (unsigned short)run;
        run += (int)v[j];
      }
    }
    int deg = run;
    lds[t] = deg; __syncthreads();
    for (int off=1; off<256; off<<=1){
      int add = (t>=off)?lds[t-off]:0;
      __syncthreads();
      lds[t] += add;
      __syncthreads();
    }
    int excl = lds[t] - deg;
    if (t==255) bsum[b] = lds[t];
    if (live) rowptr[g] = excl;             // block-local prefix
    return;
  }

  // ---- GEMM1 (MFMA): B (W1t) staged in LDS once per block; A from global x ----
  int n0 = (b - SB2)*64;
  int wv = t>>6, lane = t&63;
  int m = lane&15, q = lane>>4;
  int r0w = wv*16;

  // stage W1t [256 rows x 256B] into LDS with 264B stride (bank-conflict pad)
  for (int i=t; i<4096; i+=256){
    int row = i>>4, c16 = i&15;
    *(uint4*)(smem + (size_t)row*264 + c16*16) =
      *(const uint4*)((const char*)W1t + (size_t)row*256 + c16*16);
  }

  // A fragments direct from x (fp32 -> f16), row gr
  int gr = n0 + r0w + m; if (gr > N-1) gr = N-1;
  f16x8 afr[4];
  #pragma unroll
  for (int ks=0; ks<4; ++ks){
    const float* xp = x + (size_t)gr*128 + ks*32 + q*8;
    float4 xa = *(const float4*)(xp);
    float4 xb = *(const float4*)(xp+4);
    f16x8 a;
    a[0]=(_Float16)xa.x; a[1]=(_Float16)xa.y; a[2]=(_Float16)xa.z; a[3]=(_Float16)xa.w;
    a[4]=(_Float16)xb.x; a[5]=(_Float16)xb.y; a[6]=(_Float16)xb.z; a[7]=(_Float16)xb.w;
    afr[ks] = a;
  }
  __syncthreads();

  f32x4 acc[16];
  #pragma unroll
  for (int ct=0; ct<16; ++ct) acc[ct] = (f32x4){0.f,0.f,0.f,0.f};

  #pragma unroll
  for (int ct=0; ct<16; ++ct){
    const char* brow = smem + (size_t)(ct*16 + m)*264 + q*16;
    f16x8 b0 = *(const f16x8*)(brow);
    f16x8 b1 = *(const f16x8*)(brow + 64);
    f16x8 b2 = *(const f16x8*)(brow + 128);
    f16x8 b3 = *(const f16x8*)(brow + 192);
    acc[ct] = __builtin_amdgcn_mfma_f32_16x16x32_f16(afr[0], b0, acc[ct],0,0,0);
    acc[ct] = __builtin_amdgcn_mfma_f32_16x16x32_f16(afr[1], b1, acc[ct],0,0,0);
    acc[ct] = __builtin_amdgcn_mfma_f32_16x16x32_f16(afr[2], b2, acc[ct],0,0,0);
    acc[ct] = __builtin_amdgcn_mfma_f32_16x16x32_f16(afr[3], b3, acc[ct],0,0,0);
  }
  __syncthreads();                           // all waves done with Bs

  _Float16* Hs = (_Float16*)smem;            // [64][264] halves, 528B stride
  #pragma unroll
  for (int ct=0; ct<16; ++ct){
    #pragma unroll
    for (int r=0; r<4; ++r)
      Hs[(size_t)(r0w + q*4 + r)*264 + ct*16 + m] = (_Float16)acc[ct][r];
  }
  __syncthreads();

  for (int r=0; r<16; ++r){
    int grow = n0 + r0w + r;
    if (grow < N){
      uint2 v = *(const uint2*)((const char*)Hs + (size_t)(r0w+r)*528 + lane*8);
      *(uint2*)((char*)h1 + (size_t)grow*512 + lane*8) = v;
    }
  }

  #pragma unroll
  for (int p=t; p<512; p+=256){
    int row = p>>3, hd = p&7;
    int grow = n0 + row;
    if (grow < N){
      const _Float16* hr = Hs + (size_t)row*264 + hd*32;
      float sa=0.f, sd=0.f;
      #pragma unroll
      for (int c=0; c<32; ++c){
        float hv = (float)hr[c];
        sa += hv * as1[hd*32+c];
        sd += hv * ad1[hd*32+c];
      }
      a_src1[(size_t)grow*8+hd] = sa;
      a_dst1[(size_t)grow*8+hd] = sd;
    }
  }
}

// ---------------- K3: scatter (LDS u16 cursors) + rowfin finalize ----------------
__global__ __launch_bounds__(256) void k_scatter3(const int* __restrict__ srcv,
    const int* __restrict__ dstv, const int* __restrict__ rowptr,
    const unsigned short* __restrict__ partial3, const int* __restrict__ bsum,
    int* __restrict__ csr_src, int* __restrict__ rowfin,
    int E, int Etot, int chunk, int SB2, int N)
{
  __shared__ unsigned int cur[NWH];         // 50 KB -> 2 blocks/CU
  __shared__ int bpre[256];
  int b = blockIdx.x, t = threadIdx.x;
  int c = b >> 1, half = b & 1, lo = half*HBINS;
  for (int i=t; i<NWH; i+=256) cur[i] = 0u;
  if (t==0){ int run=0; for (int j=0;j<SB2;++j){ bpre[j]=run; run+=bsum[j]; } }
  __syncthreads();

  // finalize rowptr into rowfin (blocks 0..SB2-1; 256 bins each)
  if (b < SB2){
    int i = b*256 + t;
    if (i < N) rowfin[i] = rowptr[i] + bpre[b];
    if (b==0 && t==0) rowfin[N] = Etot;
  }

  int e0 = c*chunk, e1 = e0+chunk; if (e1 > Etot) e1 = Etot;
  int e = e0 + t;
  for (; e + 768 < e1; e += 1024){
    int ea=e, eb=e+256, ec=e+512, ed=e+768;
    int d0,s0,d1,s1,d2,s2,d3,s3;
    if (ea<E){ d0=dstv[ea]; s0=srcv[ea]; } else { d0=ea-E; s0=d0; }
    if (eb<E){ d1=dstv[eb]; s1=srcv[eb]; } else { d1=eb-E; s1=d1; }
    if (ec<E){ d2=dstv[ec]; s2=srcv[ec]; } else { d2=ec-E; s2=d2; }
    if (ed<E){ d3=dstv[ed]; s3=srcv[ed]; } else { d3=ed-E; s3=d3; }
    int r0=d0-lo, r1=d1-lo, r2=d2-lo, r3=d3-lo;
    if (r0>=0 && r0<HBINS){
      int base0 = rowptr[d0] + bpre[d0>>8] + (int)partial3[p3idx(d0,c)];
      unsigned int o0 = atomicAdd(&cur[r0>>1], (r0&1)?65536u:1u);
      csr_src[base0 + ((r0&1)?(int)(o0>>16):(int)(o0&0xffff))] = s0;
    }
    if (r1>=0 && r1<HBINS){
      int base1 = rowptr[d1] + bpre[d1>>8] + (int)partial3[p3idx(d1,c)];
      unsigned int o1 = atomicAdd(&cur[r1>>1], (r1&1)?65536u:1u);
      csr_src[base1 + ((r1&1)?(int)(o1>>16):(int)(o1&0xffff))] = s1;
    }
    if (r2>=0 && r2<HBINS){
      int base2 = rowptr[d2] + bpre[d2>>8] + (int)partial3[p3idx(d2,c)];
      unsigned int o2 = atomicAdd(&cur[r2>>1], (r2&1)?65536u:1u);
      csr_src[base2 + ((r2&1)?(int)(o2>>16):(int)(o2&0xffff))] = s2;
    }
    if (r3>=0 && r3<HBINS){
      int base3 = rowptr[d3] + bpre[d3>>8] + (int)partial3[p3idx(d3,c)];
      unsigned int o3 = atomicAdd(&cur[r3>>1], (r3&1)?65536u:1u);
      csr_src[base3 + ((r3&1)?(int)(o3>>16):(int)(o3&0xffff))] = s3;
    }
  }
  for (; e < e1; e += 256){
    int d,s;
    if (e<E){ d=dstv[e]; s=srcv[e]; } else { d=e-E; s=d; }
    int r = d - lo;
    if (r>=0 && r<HBINS){
      int base = rowptr[d] + bpre[d>>8] + (int)partial3[p3idx(d,c)];
      unsigned int o = atomicAdd(&cur[r>>1], (r&1)?65536u:1u);
      csr_src[base + ((r&1)?(int)(o>>16):(int)(o&0xffff))] = s;
    }
  }
}

// ---------------- K4: Layer-1 aggregation (wave/dst, x8/x4/x1) ----------------
__global__ __launch_bounds__(256) void k_agg1(const __half* __restrict__ h1,
    const float* __restrict__ a_src1, const float* __restrict__ a_dst1,
    const int* __restrict__ rowfin, const int* __restrict__ csr_src,
    const float* __restrict__ bias1, _Float16* __restrict__ h2f, int N)
{
  int wave = (blockIdx.x*blockDim.x + threadIdx.x) >> 6;
  if (wave >= N) return;
  int lane = threadIdx.x & 63;
  int head = lane >> 3;
  float ad = a_dst1[(size_t)wave*8 + head];
  int beg = rowfin[wave], end = rowfin[wave+1];
  float4 acc = make_float4(0.f,0.f,0.f,0.f);
  float wsum = 0.f;
  int i = beg;
  for (; i+8 <= end; i+=8){
    int s[8]; float e[8]; uint2 p[8];
    #pragma unroll
    for (int j=0;j<8;++j) s[j]=csr_src[i+j];
    #pragma unroll
    for (int j=0;j<8;++j){
      e[j]=a_src1[(size_t)s[j]*8+head];
      p[j]=*(const uint2*)((const char*)h1 + (size_t)s[j]*512 + lane*8);
    }
    #pragma unroll
    for (int j=0;j<8;++j){
      float w=__expf(lrelu(e[j]+ad));
      wsum += w;
      const __half2* qq=(const __half2*)&p[j];
      float2 f0=__half22float2(qq[0]), f1=__half22float2(qq[1]);
      acc.x += w*f0.x; acc.y += w*f0.y; acc.z += w*f1.x; acc.w += w*f1.y;
    }
  }
  for (; i+4 <= end; i+=4){
    int s[4]; float e[4]; uint2 p[4];
    #pragma unroll
    for (int j=0;j<4;++j) s[j]=csr_src[i+j];
    #pragma unroll
    for (int j=0;j<4;++j){
      e[j]=a_src1[(size_t)s[j]*8+head];
      p[j]=*(const uint2*)((const char*)h1 + (size_t)s[j]*512 + lane*8);
    }
    #pragma unroll
    for (int j=0;j<4;++j){
      float w=__expf(lrelu(e[j]+ad));
      wsum += w;
      const __half2* qq=(const __half2*)&p[j];
      float2 f0=__half22float2(qq[0]), f1=__half22float2(qq[1]);
      acc.x += w*f0.x; acc.y += w*f0.y; acc.z += w*f1.x; acc.w += w*f1.y;
    }
  }
  for (; i<end; ++i){
    int s = csr_src[i];
    float w = __expf(lrelu(a_src1[(size_t)s*8+head] + ad));
    wsum += w;
    uint2 p = *(const uint2*)((const char*)h1 + (size_t)s*512 + lane*8);
    const __half2* qq=(const __half2*)&p;
    float2 f0=__half22float2(qq[0]), f1=__half22float2(qq[1]);
    acc.x += w*f0.x; acc.y += w*f0.y; acc.z += w*f1.x; acc.w += w*f1.y;
  }
  float dinv = 1.f/(wsum + 1e-16f);
  const float4 bv = *(const float4*)(bias1 + lane*4);
  float4 o;
  o.x = acc.x*dinv + bv.x;
  o.y = acc.y*dinv + bv.y;
  o.z = acc.z*dinv + bv.z;
  o.w = acc.w*dinv + bv.w;
  o.x = o.x > 0.f ? o.x : __expf(o.x)-1.f;
  o.y = o.y > 0.f ? o.y : __expf(o.y)-1.f;
  o.z = o.z > 0.f ? o.z : __expf(o.z)-1.f;
  o.w = o.w > 0.f ? o.w : __expf(o.w)-1.f;
  f16x4 ov = { (_Float16)o.x, (_Float16)o.y, (_Float16)o.z, (_Float16)o.w };
  *(f16x4*)(h2f + (size_t)wave*256 + lane*4) = ov;
}

// ---------------- K5: GEMM2 (MFMA): hb(fp16) = h2f @ W2, + a_src2/a_dst2 ----------------
__global__ __launch_bounds__(256) void k_gemm2(const _Float16* __restrict__ h2f,
    const _Float16* __restrict__ W2t, const float* __restrict__ as2, const float* __restrict__ ad2,
    _Float16* __restrict__ hbh, float* __restrict__ a_src2, float* __restrict__ a_dst2, int N)
{
  int t = threadIdx.x, wv = t>>6, lane = t&63;
  int col = lane&15, q = lane>>4;
  int n0 = blockIdx.x*64 + wv*16;
  int am = n0 + col; if (am > N-1) am = N-1;

  const _Float16* arow = h2f + (size_t)am*256 + q*8;
  const _Float16* brow = W2t + (size_t)col*256 + q*8;
  f32x4 acc = (f32x4){0.f,0.f,0.f,0.f};
  #pragma unroll
  for (int ks=0; ks<8; ++ks){
    f16x8 a = *(const f16x8*)(arow + ks*32);
    f16x8 b = *(const f16x8*)(brow + ks*32);
    acc = __builtin_amdgcn_mfma_f32_16x16x32_f16(a, b, acc, 0,0,0);
  }

  float vs = as2[col], vd = ad2[col];
  #pragma unroll
  for (int r=0; r<4; ++r){
    int n = n0 + q*4 + r;
    float v = acc[r];
    float pa = v*vs, pd = v*vd;
    #pragma unroll
    for (int msk=8; msk>=1; msk>>=1){ pa += __shfl_xor(pa,msk); pd += __shfl_xor(pd,msk); }
    if (n < N){
      hbh[(size_t)n*16 + col] = (_Float16)v;
      if (col==0){ a_src2[n] = pa; a_dst2[n] = pd; }
    }
  }
}

// ---------------- K6: Layer-2 aggregation: wave per dst, 4 edge-groups x 16 ch ----------------
__global__ __launch_bounds__(256) void k_agg2(const __half* __restrict__ hbh,
    const float* __restrict__ a_src2, const float* __restrict__ a_dst2,
    const int* __restrict__ rowfin, const int* __restrict__ csr_src,
    const float* __restrict__ bias2, float* __restrict__ out, int N)
{
  int wave = (blockIdx.x*blockDim.x + threadIdx.x) >> 6;
  if (wave >= N) return;
  int lane = threadIdx.x & 63;
  int eg   = lane >> 4;
  int ch   = lane & 15;
  float ad = a_dst2[wave];
  int beg = rowfin[wave], end = rowfin[wave+1];
  float acc = 0.f, wsum = 0.f;
  int i = beg + eg;
  for (; i+4 < end; i+=8){
    int s0 = csr_src[i], s1 = csr_src[i+4];
    float e0 = a_src2[s0], e1 = a_src2[s1];
    float h0 = __half2float(hbh[(size_t)s0*16 + ch]);
    float h1v = __half2float(hbh[(size_t)s1*16 + ch]);
    float w0 = __expf(lrelu(e0 + ad)), w1 = __expf(lrelu(e1 + ad));
    wsum += w0 + w1;
    acc += w0*h0 + w1*h1v;
  }
  for (; i<end; i+=4){
    int s = csr_src[i];
    float w = __expf(lrelu(a_src2[s] + ad));
    wsum += w;
    acc += w * __half2float(hbh[(size_t)s*16 + ch]);
  }
  acc  += __shfl_xor(acc, 16);  acc  += __shfl_xor(acc, 32);
  wsum += __shfl_xor(wsum, 16); wsum += __shfl_xor(wsum, 32);
  if (eg == 0)
    out[(size_t)wave*16 + ch] = acc/(wsum + 1e-16f) + bias2[ch];
}

extern "C" void kernel_launch(void* const* d_in, const int* in_sizes, int n_in,
                              void* d_out, int out_size, void* d_ws, size_t ws_size,
                              hipStream_t stream)
{
  const float* x   = (const float*)d_in[0];
  const int*   ei  = (const int*)  d_in[1];
  const float* W1  = (const float*)d_in[2];
  const float* as1 = (const float*)d_in[3];
  const float* ad1 = (const float*)d_in[4];
  const float* b1  = (const float*)d_in[5];
  const float* W2  = (const float*)d_in[6];
  const float* as2 = (const float*)d_in[7];
  const float* ad2 = (const float*)d_in[8];
  const float* b2  = (const float*)d_in[9];
  float* out = (float*)d_out;

  const int N    = in_sizes[0] / 128;       // 50000
  const int E    = in_sizes[1] / 2;         // 800000
  const int Etot = E + N;
  const int* srcv = ei;
  const int* dstv = ei + E;
  const int chunk = (Etot + NC - 1) / NC;   // 6641 < 65536 (u16-field safe)
  const int SB2   = (N + 255) / 256;        // 196 scan blocks (256 bins each)
  const int TN    = (N + 63) / 64;          // 782 gemm1 tiles

  char* p = (char*)d_ws;
  auto alloc = [&](size_t bytes)->void* {
    void* r = (void*)p;
    p += (bytes + 255) & ~((size_t)255);
    return r;
  };
  _Float16* h1   = (_Float16*)alloc((size_t)N*256*sizeof(_Float16));
  _Float16* W1t  = (_Float16*)alloc((size_t)256*128*sizeof(_Float16));
  _Float16* h2f  = (_Float16*)alloc((size_t)N*256*sizeof(_Float16));
  _Float16* W2t  = (_Float16*)alloc((size_t)16*256*sizeof(_Float16));
  _Float16* hbh  = (_Float16*)alloc((size_t)N*16*sizeof(_Float16));
  float* a_src1  = (float*)alloc((size_t)N*8*sizeof(float));
  float* a_dst1  = (float*)alloc((size_t)N*8*sizeof(float));
  float* a_src2  = (float*)alloc((size_t)N*sizeof(float));
  float* a_dst2  = (float*)alloc((size_t)N*sizeof(float));
  int*   rowptr  = (int*)alloc((size_t)(N+1)*sizeof(int));
  int*   rowfin  = (int*)alloc((size_t)(N+1)*sizeof(int));
  int*   bsum    = (int*)alloc(256*sizeof(int));
  unsigned short* partial3 = (unsigned short*)alloc((size_t)NTILE*128*64*sizeof(unsigned short));
  int*   csr_src = (int*)alloc((size_t)Etot*sizeof(int));

  // K1: histogram (chunk x half, 256 blocks) -> tile-major partial3 + weight prep
  k_histW<<<dim3(NBK+129), dim3(256), 0, stream>>>(dstv, partial3, E, Etot, chunk,
                                                   W1, W1t, W2, W2t);
  // K2: scan (tile-streaming; blocks 0..SB2-1) + gemm1 (LDS-B; blocks SB2..)
  k_g1scan<<<dim3(SB2 + TN), dim3(256), 0, stream>>>(x, W1t, as1, ad1, h1,
      a_src1, a_dst1, partial3, rowptr, bsum, N, SB2);
  // K3: scatter + rowfin finalize
  k_scatter3<<<dim3(NBK), dim3(256), 0, stream>>>(srcv, dstv, rowptr,
      partial3, bsum, csr_src, rowfin, E, Etot, chunk, SB2, N);
  // K4: agg1
  k_agg1<<<dim3((N + 3)/4), dim3(256), 0, stream>>>((const __half*)h1, a_src1, a_dst1,
      rowfin, csr_src, b1, h2f, N);
  // K5: gemm2 (fp16 hb)
  k_gemm2<<<dim3((N + 63)/64), dim3(256), 0, stream>>>(h2f, W2t, as2, ad2, hbh, a_src2, a_dst2, N);
  // K6: agg2
  k_agg2<<<dim3((N + 3)/4), dim3(256), 0, stream>>>((const __half*)hbh, a_src2, a_dst2,
      rowfin, csr_src, b2, out, N);
}